// Round 1
// baseline (9562.253 us; speedup 1.0000x reference)
//
#include <hip/hip_runtime.h>
#include <math.h>

#define BB 64
#define TT 4096
#define IN0 32
#define HH 128
#define G3 384   // 3*H
#define NOUT 32

__device__ __forceinline__ float fast_sigmoid(float x) {
    x = fminf(fmaxf(x, -30.f), 30.f);
    float e = __expf(-x);
    return __builtin_amdgcn_rcpf(1.f + e);
}
__device__ __forceinline__ float fast_tanh(float x) {
    x = fminf(fmaxf(x, -15.f), 15.f);
    float e = __expf(-2.f * x);
    return (1.f - e) * __builtin_amdgcn_rcpf(1.f + e);
}

// One workgroup per batch element. 768 threads: thread t handles row r = t%384
// of the 3H gate pre-activations, K-half = t/384 (64 of the 128 hh-dot terms,
// IN_K/2 of the input-projection terms). Weights live in VGPRs; h lives in LDS.
template<int IN_K>
__global__ __launch_bounds__(768) void gru_layer_kernel(
    const float* __restrict__ in,    // [B, T, IN_K]
    const float* __restrict__ W_ih,  // [384, IN_K]
    const float* __restrict__ W_hh,  // [384, 128]
    const float* __restrict__ b_ih,  // [384]
    const float* __restrict__ b_hh,  // [384]
    float* __restrict__ y,           // [B, T, 128]  (may alias `in` shifted-in-time safely)
    float* __restrict__ h_out)       // [B, 128] final hidden
{
    constexpr int KI = IN_K / 2;     // per-thread input-proj K extent
    const int b = blockIdx.x;
    const int tid = threadIdx.x;
    const int half = (tid >= G3) ? 1 : 0;   // wave-uniform (384 = 6 waves)
    const int r = tid - half * G3;          // 0..383

    // ---- weights into registers ----
    float whh[64];
    #pragma unroll
    for (int k = 0; k < 64; ++k) whh[k] = W_hh[r * HH + half * 64 + k];
    float wih[KI];
    #pragma unroll
    for (int k = 0; k < KI; ++k) wih[k] = W_ih[r * IN_K + half * KI + k];
    const float bias_gi = (half == 0) ? b_ih[r] : 0.f;
    const float bias_gh = (half == 0) ? b_hh[r] : 0.f;

    __shared__ float xs[2][IN_K];
    __shared__ float hs[HH];
    __shared__ float pgi[2][G3];
    __shared__ float pgh[2][G3];

    const float* inb = in + (size_t)b * TT * IN_K;
    float* yb = y + (size_t)b * TT * HH;

    if (tid < HH) hs[tid] = 0.f;
    if (tid < IN_K) xs[0][tid] = inb[tid];
    __syncthreads();

    int cur = 0;
    const int pidx = tid - HH;   // prefetch lane index (threads 128..128+IN_K-1)

    for (int t = 0; t < TT; ++t) {
        // issue next-step input load early (latency hides under the matvec)
        float pre = 0.f;
        if (pidx >= 0 && pidx < IN_K) {
            const int tn = (t + 1 < TT) ? (t + 1) : t;   // clamp; value unused at t=T-1
            pre = inb[(size_t)tn * IN_K + pidx];
        }

        // ---- matvec phase: two accumulators each to break fma dep chains ----
        float agh0 = bias_gh, agh1 = 0.f;
        {
            const float4* h4 = (const float4*)&hs[half * 64];
            #pragma unroll
            for (int k4 = 0; k4 < 16; k4 += 2) {
                float4 a = h4[k4];
                float4 c = h4[k4 + 1];
                agh0 = fmaf(whh[4*k4+0], a.x, agh0);
                agh0 = fmaf(whh[4*k4+1], a.y, agh0);
                agh0 = fmaf(whh[4*k4+2], a.z, agh0);
                agh0 = fmaf(whh[4*k4+3], a.w, agh0);
                agh1 = fmaf(whh[4*k4+4], c.x, agh1);
                agh1 = fmaf(whh[4*k4+5], c.y, agh1);
                agh1 = fmaf(whh[4*k4+6], c.z, agh1);
                agh1 = fmaf(whh[4*k4+7], c.w, agh1);
            }
        }
        float agi0 = bias_gi, agi1 = 0.f;
        {
            const float4* x4 = (const float4*)&xs[cur][half * KI];
            #pragma unroll
            for (int k4 = 0; k4 < KI / 4; k4 += 2) {
                float4 a = x4[k4];
                float4 c = x4[k4 + 1];
                agi0 = fmaf(wih[4*k4+0], a.x, agi0);
                agi0 = fmaf(wih[4*k4+1], a.y, agi0);
                agi0 = fmaf(wih[4*k4+2], a.z, agi0);
                agi0 = fmaf(wih[4*k4+3], a.w, agi0);
                agi1 = fmaf(wih[4*k4+4], c.x, agi1);
                agi1 = fmaf(wih[4*k4+5], c.y, agi1);
                agi1 = fmaf(wih[4*k4+6], c.z, agi1);
                agi1 = fmaf(wih[4*k4+7], c.w, agi1);
            }
        }
        pgh[half][r] = agh0 + agh1;
        pgi[half][r] = agi0 + agi1;
        __syncthreads();

        // ---- gate phase (waves 0-1) + next-input LDS store (waves 2..) ----
        if (tid < HH) {
            const int j = tid;
            float gi_r = pgi[0][j]        + pgi[1][j];
            float gi_z = pgi[0][j + HH]   + pgi[1][j + HH];
            float gi_n = pgi[0][j + 2*HH] + pgi[1][j + 2*HH];
            float gh_r = pgh[0][j]        + pgh[1][j];
            float gh_z = pgh[0][j + HH]   + pgh[1][j + HH];
            float gh_n = pgh[0][j + 2*HH] + pgh[1][j + 2*HH];
            float rg = fast_sigmoid(gi_r + gh_r);
            float zg = fast_sigmoid(gi_z + gh_z);
            float ng = fast_tanh(gi_n + rg * gh_n);
            float hn = (1.f - zg) * ng + zg * hs[j];
            hs[j] = hn;
            yb[(size_t)t * HH + j] = hn;
            if (t == TT - 1) h_out[b * HH + j] = hn;
        } else if (pidx >= 0 && pidx < IN_K) {
            xs[cur ^ 1][pidx] = pre;
        }
        __syncthreads();
        cur ^= 1;
    }
}

// out[bt, o] = fc_b[o] + sum_k y1[bt, k] * fc_w[o, k]; 8 rows per 256-thread block
__global__ __launch_bounds__(256) void fc_kernel(
    const float* __restrict__ y1,    // [B*T, 128]
    const float* __restrict__ fc_w,  // [32, 128]
    const float* __restrict__ fc_b,  // [32]
    float* __restrict__ out)         // [B*T, 32]
{
    __shared__ float wT[HH][NOUT];   // transposed: wT[k][o]
    __shared__ float ys[8][HH];
    __shared__ float bsh[NOUT];
    const int tid = threadIdx.x;

    for (int i = tid; i < NOUT * HH; i += 256) {
        int o = i >> 7, k = i & 127;
        wT[k][o] = fc_w[i];
    }
    if (tid < NOUT) bsh[tid] = fc_b[tid];

    const size_t row0 = (size_t)blockIdx.x * 8;
    for (int i = tid; i < 8 * HH; i += 256) {
        ys[i >> 7][i & 127] = y1[(row0 + (i >> 7)) * HH + (i & 127)];
    }
    __syncthreads();

    const int o = tid & 31, rloc = tid >> 5;
    float acc = bsh[o];
    #pragma unroll
    for (int k = 0; k < HH; ++k) acc = fmaf(ys[rloc][k], wT[k][o], acc);
    out[(row0 + rloc) * NOUT + o] = acc;
}

extern "C" void kernel_launch(void* const* d_in, const int* in_sizes, int n_in,
                              void* d_out, int out_size, void* d_ws, size_t ws_size,
                              hipStream_t stream) {
    const float* x     = (const float*)d_in[0];
    const float* W_ih0 = (const float*)d_in[1];
    const float* W_hh0 = (const float*)d_in[2];
    const float* b_ih0 = (const float*)d_in[3];
    const float* b_hh0 = (const float*)d_in[4];
    const float* W_ih1 = (const float*)d_in[5];
    const float* W_hh1 = (const float*)d_in[6];
    const float* b_ih1 = (const float*)d_in[7];
    const float* b_hh1 = (const float*)d_in[8];
    const float* fc_w  = (const float*)d_in[9];
    const float* fc_b  = (const float*)d_in[10];

    float* out    = (float*)d_out;                      // [B,T,32]
    float* hstack = out + (size_t)BB * TT * NOUT;       // [2,B,128]
    float* ybuf   = (float*)d_ws;                       // [B,T,128], reused in place by layer 1

    gru_layer_kernel<IN0><<<BB, 768, 0, stream>>>(
        x, W_ih0, W_hh0, b_ih0, b_hh0, ybuf, hstack);
    gru_layer_kernel<HH><<<BB, 768, 0, stream>>>(
        ybuf, W_ih1, W_hh1, b_ih1, b_hh1, ybuf, hstack + BB * HH);
    fc_kernel<<<(BB * TT) / 8, 256, 0, stream>>>(ybuf, fc_w, fc_b, out);
}

// Round 2
// 6653.559 us; speedup vs baseline: 1.4372x; 1.4372x over previous
//
#include <hip/hip_runtime.h>

#define BB 64
#define TT 4096
#define IN0 32
#define HH 128
#define G3 384
#define NOUT 32

typedef float v2f __attribute__((ext_vector_type(2)));
typedef unsigned short ushort_t;

struct SM {
    float xs[2][HH];          // staged input for current/next step (fp32)
    float hs[2][HH];          // hidden state double buffer
    float pg[2][G3];          // rows 0..255: gi+gh combined (r,z); rows 256..383: gi_n
    float pghn[2][HH];        // gh_n partials
    float fcw[NOUT * 132];    // fc weights, stride 132 (bank-conflict pad), [o*132+128]=bias
    float pfc[NOUT * 9];      // fc partials, stride 9
};

__device__ __forceinline__ float fast_sigmoid(float x) {
    x = fminf(fmaxf(x, -30.f), 30.f);
    float e = __expf(-x);
    return __builtin_amdgcn_rcpf(1.f + e);
}
__device__ __forceinline__ float fast_tanh(float x) {
    x = fminf(fmaxf(x, -15.f), 15.f);
    float e = __expf(-2.f * x);
    return (1.f - e) * __builtin_amdgcn_rcpf(1.f + e);
}
__device__ __forceinline__ float bf2f(ushort_t u) {
    return __uint_as_float((unsigned)u << 16);
}
__device__ __forceinline__ ushort_t f2bf(float f) {  // RNE
    unsigned u = __float_as_uint(f);
    return (ushort_t)((u + 0x7FFFu + ((u >> 16) & 1u)) >> 16);
}
__device__ __forceinline__ v2f mkv2(float a, float b) { v2f r; r.x = a; r.y = b; return r; }

// ROLE: L1=false -> layer-0 producer (reads x fp32, writes y0 bf16 + flag)
//       L1=true  -> layer-1 consumer (waits flag, reads y0 bf16, fused fc -> out)
template<int IN_K, bool L1>
__device__ __forceinline__ void gru_role(
    SM& sm, const void* in_, const float* __restrict__ W_ih, const float* __restrict__ W_hh,
    const float* __restrict__ b_ih, const float* __restrict__ b_hh,
    ushort_t* __restrict__ y0w,      // producer: y0 bf16 base
    float* __restrict__ hout,        // [H] final hidden for this batch
    float* __restrict__ outb,        // consumer: out + b*T*NOUT
    const float* __restrict__ fc_w, const float* __restrict__ fc_b,
    int* flag, int b)
{
    constexpr int KI = IN_K / 2;     // per-thread K extent for input projection
    constexpr int NV = IN_K / 4;     // float4/ushort4 vectors per input row
    const int tid = threadIdx.x;
    const int kh = (tid >= G3) ? 1 : 0;   // K-half (wave-uniform: 384 = 6 waves)
    const int r = tid - kh * G3;          // gate row 0..383

    // ---- weights into VGPRs (as v2f pairs for v_pk_fma_f32) ----
    v2f whh[32];
    {
        const float4* w4 = (const float4*)(W_hh + r * HH + kh * 64);
        #pragma unroll
        for (int k = 0; k < 16; ++k) {
            float4 w = w4[k];
            whh[2 * k] = mkv2(w.x, w.y);
            whh[2 * k + 1] = mkv2(w.z, w.w);
        }
    }
    v2f wih[KI / 2];
    {
        const float4* w4 = (const float4*)(W_ih + r * IN_K + kh * KI);
        #pragma unroll
        for (int k = 0; k < KI / 4; ++k) {
            float4 w = w4[k];
            wih[2 * k] = mkv2(w.x, w.y);
            wih[2 * k + 1] = mkv2(w.z, w.w);
        }
    }
    const float bgi = kh ? 0.f : b_ih[r];
    const float bgh = kh ? 0.f : b_hh[r];

    const float*    inb_f = (const float*)in_ + (size_t)b * TT * IN_K;    // producer
    const ushort_t* inb_u = (const ushort_t*)in_ + (size_t)b * TT * HH;   // consumer
    ushort_t* y0b = L1 ? nullptr : (y0w + (size_t)b * TT * HH);

    // ---- LDS init ----
    if (tid < HH) sm.hs[0][tid] = 0.f;
    if constexpr (L1) {
        for (int i = tid; i < NOUT * HH; i += 768)
            sm.fcw[(i >> 7) * 132 + (i & 127)] = fc_w[i];
        if (tid < NOUT) sm.fcw[tid * 132 + 128] = fc_b[tid];
        if (tid == 0) {   // initial wait: 2 chunks ahead
            while (__hip_atomic_load(flag, __ATOMIC_RELAXED, __HIP_MEMORY_SCOPE_AGENT) < 16)
                __builtin_amdgcn_s_sleep(2);
            __threadfence();
        }
    }
    __syncthreads();
    if (tid < NV) {  // stage x(t=0)
        if constexpr (L1) {
            ushort4 u = ((const ushort4*)inb_u)[tid];
            float4 f; f.x = bf2f(u.x); f.y = bf2f(u.y); f.z = bf2f(u.z); f.w = bf2f(u.w);
            ((float4*)sm.xs[0])[tid] = f;
        } else {
            ((float4*)sm.xs[0])[tid] = ((const float4*)inb_f)[tid];
        }
    }
    __syncthreads();

    int cur = 0;
    const int pidx = tid - 128;   // prefetch vector lane in [0, NV)

    for (int t = 0; t < TT; ++t) {
        // ---- chunk sync (consumer): stay 2 chunks behind producer ----
        if (L1 && t && (t & 7) == 0) {
            if (tid == 0) {
                int target = t + 16; if (target > TT) target = TT;
                while (__hip_atomic_load(flag, __ATOMIC_RELAXED, __HIP_MEMORY_SCOPE_AGENT) < target)
                    __builtin_amdgcn_s_sleep(2);
                __threadfence();
            }
            __syncthreads();
        }

        // ---- fc reduce for step t-2 (consumer, half of wave 11) ----
        if (L1 && t >= 2 && tid >= 704 && tid < 736) {
            int o = tid - 704;
            float s = sm.fcw[o * 132 + 128];
            #pragma unroll
            for (int j = 0; j < 8; ++j) s += sm.pfc[o * 9 + j];
            outb[(size_t)(t - 2) * NOUT + o] = s;
        }

        // ---- issue next-step input load early ----
        float4 pf; ushort4 pu;
        if (pidx >= 0 && pidx < NV) {
            int tn = (t + 1 < TT) ? t + 1 : t;
            if constexpr (L1) pu = ((const ushort4*)(inb_u + (size_t)tn * HH))[pidx];
            else              pf = ((const float4*)(inb_f + (size_t)tn * IN_K))[pidx];
        }

        // ---- matvec: gh (K=128 split 2) and gi (K=IN_K split 2), pk-fma ----
        v2f a0 = mkv2(bgh, 0.f), a1 = mkv2(0.f, 0.f);
        {
            const float4* h4 = (const float4*)&sm.hs[cur][kh * 64];
            #pragma unroll
            for (int k = 0; k < 16; k += 2) {
                float4 x0 = h4[k], x1 = h4[k + 1];
                a0 += whh[2 * k] * mkv2(x0.x, x0.y);
                a0 += whh[2 * k + 1] * mkv2(x0.z, x0.w);
                a1 += whh[2 * k + 2] * mkv2(x1.x, x1.y);
                a1 += whh[2 * k + 3] * mkv2(x1.z, x1.w);
            }
        }
        float sgh = a0.x + a0.y + a1.x + a1.y;
        v2f c0 = mkv2(bgi, 0.f), c1 = mkv2(0.f, 0.f);
        {
            const float4* x4 = (const float4*)&sm.xs[cur][kh * KI];
            #pragma unroll
            for (int k = 0; k < KI / 4; k += 2) {
                float4 x0 = x4[k], x1 = x4[k + 1];
                c0 += wih[2 * k] * mkv2(x0.x, x0.y);
                c0 += wih[2 * k + 1] * mkv2(x0.z, x0.w);
                c1 += wih[2 * k + 2] * mkv2(x1.x, x1.y);
                c1 += wih[2 * k + 3] * mkv2(x1.z, x1.w);
            }
        }
        float sgi = c0.x + c0.y + c1.x + c1.y;
        if (r < 2 * HH) {                 // r,z rows: only the sum is needed
            sm.pg[kh][r] = sgi + sgh;
        } else {                          // n rows: keep gi_n / gh_n separate
            sm.pg[kh][r] = sgi;
            sm.pghn[kh][r - 2 * HH] = sgh;
        }
        __syncthreads();

        const int nxt = cur ^ 1;
        // ---- gates (waves 0-1) / input stage (wave 2) / fc partials (waves 6-9) ----
        if (tid < HH) {
            const int j = tid;
            float g_r = sm.pg[0][j] + sm.pg[1][j];
            float g_z = sm.pg[0][j + HH] + sm.pg[1][j + HH];
            float gin = sm.pg[0][j + 2 * HH] + sm.pg[1][j + 2 * HH];
            float ghn = sm.pghn[0][j] + sm.pghn[1][j];
            float rg = fast_sigmoid(g_r);
            float zg = fast_sigmoid(g_z);
            float ng = fast_tanh(gin + rg * ghn);
            float hn = (1.f - zg) * ng + zg * sm.hs[cur][j];
            sm.hs[nxt][j] = hn;
            if (!L1) y0b[(size_t)t * HH + j] = f2bf(hn);
            if (t == TT - 1) hout[j] = hn;
        } else if (pidx >= 0 && pidx < NV) {
            if constexpr (L1) {
                float4 f; f.x = bf2f(pu.x); f.y = bf2f(pu.y); f.z = bf2f(pu.z); f.w = bf2f(pu.w);
                ((float4*)sm.xs[nxt])[pidx] = f;
            } else {
                ((float4*)sm.xs[nxt])[pidx] = pf;
            }
        }
        if (L1 && tid >= 384 && tid < 640) {   // fc partials for h_{t-1} = hs[cur]
            int idx = tid - 384, o = idx >> 3, ks = idx & 7;
            const float* hv = &sm.hs[cur][ks * 16];
            const float* wv = &sm.fcw[o * 132 + ks * 16];
            float s = 0.f;
            #pragma unroll
            for (int i = 0; i < 16; ++i) s = fmaf(hv[i], wv[i], s);
            sm.pfc[o * 9 + ks] = s;
        }
        __syncthreads();

        // ---- producer: publish progress every 8 steps (after barrier drains y0 stores) ----
        if (!L1 && (t & 7) == 7 && tid == 0) {
            __threadfence();
            __hip_atomic_store(flag, t + 1, __ATOMIC_RELAXED, __HIP_MEMORY_SCOPE_AGENT);
        }
        cur = nxt;
    }

    // ---- consumer epilogue: flush fc pipeline (steps TT-2, TT-1) ----
    if constexpr (L1) {
        if (tid >= 704 && tid < 736) {
            int o = tid - 704;
            float s = sm.fcw[o * 132 + 128];
            #pragma unroll
            for (int j = 0; j < 8; ++j) s += sm.pfc[o * 9 + j];
            outb[(size_t)(TT - 2) * NOUT + o] = s;
        }
        __syncthreads();
        if (tid >= 384 && tid < 640) {   // partials for h_{TT-1} = hs[cur]
            int idx = tid - 384, o = idx >> 3, ks = idx & 7;
            const float* hv = &sm.hs[cur][ks * 16];
            const float* wv = &sm.fcw[o * 132 + ks * 16];
            float s = 0.f;
            #pragma unroll
            for (int i = 0; i < 16; ++i) s = fmaf(hv[i], wv[i], s);
            sm.pfc[o * 9 + ks] = s;
        }
        __syncthreads();
        if (tid >= 704 && tid < 736) {
            int o = tid - 704;
            float s = sm.fcw[o * 132 + 128];
            #pragma unroll
            for (int j = 0; j < 8; ++j) s += sm.pfc[o * 9 + j];
            outb[(size_t)(TT - 1) * NOUT + o] = s;
        }
    }
}

extern "C" __global__ void __launch_bounds__(768)
__attribute__((amdgpu_waves_per_eu(3, 3)))   // pin 1 WG/CU: VGPR budget ~168, keep weights resident
gru_fused_kernel(
    const float* x,
    const float* W_ih0, const float* W_hh0, const float* b_ih0, const float* b_hh0,
    const float* W_ih1, const float* W_hh1, const float* b_ih1, const float* b_hh1,
    const float* fc_w, const float* fc_b,
    float* out, float* hstack, ushort_t* y0, int* flags)
{
    __shared__ SM sm;
    const int wg = blockIdx.x;
    if (wg < BB) {
        gru_role<IN0, false>(sm, x, W_ih0, W_hh0, b_ih0, b_hh0,
                             y0, hstack + wg * HH, nullptr, nullptr, nullptr,
                             flags + wg, wg);
    } else {
        const int b = wg - BB;
        gru_role<HH, true>(sm, y0, W_ih1, W_hh1, b_ih1, b_hh1,
                           nullptr, hstack + BB * HH + b * HH,
                           out + (size_t)b * TT * NOUT, fc_w, fc_b,
                           flags + b, b);
    }
}

extern "C" void kernel_launch(void* const* d_in, const int* in_sizes, int n_in,
                              void* d_out, int out_size, void* d_ws, size_t ws_size,
                              hipStream_t stream) {
    const float* x     = (const float*)d_in[0];
    const float* W_ih0 = (const float*)d_in[1];
    const float* W_hh0 = (const float*)d_in[2];
    const float* b_ih0 = (const float*)d_in[3];
    const float* b_hh0 = (const float*)d_in[4];
    const float* W_ih1 = (const float*)d_in[5];
    const float* W_hh1 = (const float*)d_in[6];
    const float* b_ih1 = (const float*)d_in[7];
    const float* b_hh1 = (const float*)d_in[8];
    const float* fc_w  = (const float*)d_in[9];
    const float* fc_b  = (const float*)d_in[10];

    float* out    = (float*)d_out;                       // [B,T,32]
    float* hstack = out + (size_t)BB * TT * NOUT;        // [2,B,128]
    ushort_t* y0  = (ushort_t*)d_ws;                     // [B,T,128] bf16 (67 MB)
    int* flags    = (int*)((char*)d_ws + (96u << 20));   // 96 MB offset (< proven 128 MB ws);
                                                         // poison 0xAA.. is negative as int -> consumer blocks

    gru_fused_kernel<<<2 * BB, 768, 0, stream>>>(
        x, W_ih0, W_hh0, b_ih0, b_hh0,
        W_ih1, W_hh1, b_ih1, b_hh1,
        fc_w, fc_b, out, hstack, y0, flags);
}

// Round 3
// 5515.887 us; speedup vs baseline: 1.7336x; 1.2063x over previous
//
#include <hip/hip_runtime.h>

#define BB 64
#define TT 4096
#define IN0 32
#define HH 128
#define G3 384
#define NOUT 32

typedef float v2f __attribute__((ext_vector_type(2)));
typedef unsigned short ushort_t;

struct SM {
    float xs[2][HH];          // staged input for current/next step (fp32)
    float hs[2][HH];          // hidden state double buffer
    float pg[2][G3];          // rows 0..255: gi+gh combined (r,z); rows 256..383: gi_n
    float pghn[2][HH];        // gh_n partials
    float fcw[NOUT * 129];    // fc weights, stride 129: bank(o*129+k) = (o+k)%32 -> conflict-free
    float fcb[NOUT];          // fc bias
    float pfc[NOUT * 9];      // fc partials, stride 9 (9 coprime 32 -> <=2-way, free)
};

__device__ __forceinline__ float fast_sigmoid(float x) {
    x = fminf(fmaxf(x, -30.f), 30.f);
    float e = __expf(-x);
    return __builtin_amdgcn_rcpf(1.f + e);
}
__device__ __forceinline__ float fast_tanh(float x) {
    x = fminf(fmaxf(x, -15.f), 15.f);
    float e = __expf(-2.f * x);
    return (1.f - e) * __builtin_amdgcn_rcpf(1.f + e);
}
__device__ __forceinline__ float bf2f(ushort_t u) {
    return __uint_as_float((unsigned)u << 16);
}
__device__ __forceinline__ ushort_t f2bf(float f) {  // RNE
    unsigned u = __float_as_uint(f);
    return (ushort_t)((u + 0x7FFFu + ((u >> 16) & 1u)) >> 16);
}
__device__ __forceinline__ v2f mkv2(float a, float b) { v2f r; r.x = a; r.y = b; return r; }

// ROLE: L1=false -> layer-0 producer (reads x fp32, writes y0 bf16 + flag)
//       L1=true  -> layer-1 consumer (waits flag, reads y0 bf16, fused fc -> out)
template<int IN_K, bool L1>
__device__ __forceinline__ void gru_role(
    SM& sm, const void* in_, const float* __restrict__ W_ih, const float* __restrict__ W_hh,
    const float* __restrict__ b_ih, const float* __restrict__ b_hh,
    ushort_t* __restrict__ y0w,      // producer: y0 bf16 base
    float* __restrict__ hout,        // [H] final hidden for this batch
    float* __restrict__ outb,        // consumer: out + b*T*NOUT
    const float* __restrict__ fc_w, const float* __restrict__ fc_b,
    int* flag, int b)
{
    constexpr int KI = IN_K / 2;     // per-thread K extent for input projection
    constexpr int NV = IN_K / 4;     // float4/ushort4 vectors per input row
    const int tid = threadIdx.x;
    const int kh = (tid >= G3) ? 1 : 0;   // K-half (wave-uniform: 384 = 6 waves)
    const int r = tid - kh * G3;          // gate row 0..383

    // ---- weights into VGPRs (as v2f pairs for v_pk_fma_f32) ----
    v2f whh[32];
    {
        const float4* w4 = (const float4*)(W_hh + r * HH + kh * 64);
        #pragma unroll
        for (int k = 0; k < 16; ++k) {
            float4 w = w4[k];
            whh[2 * k] = mkv2(w.x, w.y);
            whh[2 * k + 1] = mkv2(w.z, w.w);
        }
    }
    v2f wih[KI / 2];
    {
        const float4* w4 = (const float4*)(W_ih + r * IN_K + kh * KI);
        #pragma unroll
        for (int k = 0; k < KI / 4; ++k) {
            float4 w = w4[k];
            wih[2 * k] = mkv2(w.x, w.y);
            wih[2 * k + 1] = mkv2(w.z, w.w);
        }
    }
    const float bgi = kh ? 0.f : b_ih[r];
    const float bgh = kh ? 0.f : b_hh[r];

    const float*    inb_f = (const float*)in_ + (size_t)b * TT * IN_K;    // producer
    const ushort_t* inb_u = (const ushort_t*)in_ + (size_t)b * TT * HH;   // consumer
    ushort_t* y0b = L1 ? nullptr : (y0w + (size_t)b * TT * HH);

    // ---- LDS init ----
    if (tid < HH) sm.hs[0][tid] = 0.f;
    if constexpr (L1) {
        for (int i = tid; i < NOUT * HH; i += 768)
            sm.fcw[(i >> 7) * 129 + (i & 127)] = fc_w[i];
        if (tid < NOUT) sm.fcb[tid] = fc_b[tid];
        if (tid == 0) {   // initial wait: 2 chunks ahead
            while (__hip_atomic_load(flag, __ATOMIC_RELAXED, __HIP_MEMORY_SCOPE_AGENT) < 16)
                __builtin_amdgcn_s_sleep(2);
            __threadfence();
        }
    }
    __syncthreads();
    if (tid < NV) {  // stage x(t=0)
        if constexpr (L1) {
            ushort4 u = ((const ushort4*)inb_u)[tid];
            float4 f; f.x = bf2f(u.x); f.y = bf2f(u.y); f.z = bf2f(u.z); f.w = bf2f(u.w);
            ((float4*)sm.xs[0])[tid] = f;
        } else {
            ((float4*)sm.xs[0])[tid] = ((const float4*)inb_f)[tid];
        }
    }
    __syncthreads();

    int cur = 0;
    const int pidx = tid - 128;   // prefetch vector lane in [0, NV)

    for (int t = 0; t < TT; ++t) {
        // ---- chunk sync (consumer): stay 2 chunks behind producer ----
        if (L1 && t && (t & 7) == 0) {
            if (tid == 0) {
                int target = t + 16; if (target > TT) target = TT;
                while (__hip_atomic_load(flag, __ATOMIC_RELAXED, __HIP_MEMORY_SCOPE_AGENT) < target)
                    __builtin_amdgcn_s_sleep(2);
                __threadfence();
            }
            __syncthreads();
        }

        // ---- fc reduce for step t-2 (consumer, half of wave 11) ----
        if (L1 && t >= 2 && tid >= 704 && tid < 736) {
            int o = tid - 704;
            float s = sm.fcb[o];
            #pragma unroll
            for (int j = 0; j < 8; ++j) s += sm.pfc[o * 9 + j];
            outb[(size_t)(t - 2) * NOUT + o] = s;
        }

        // ---- issue next-step input load early ----
        float4 pf; ushort4 pu;
        if (pidx >= 0 && pidx < NV) {
            int tn = (t + 1 < TT) ? t + 1 : t;
            if constexpr (L1) pu = ((const ushort4*)(inb_u + (size_t)tn * HH))[pidx];
            else              pf = ((const float4*)(inb_f + (size_t)tn * IN_K))[pidx];
        }

        // ---- matvec: gh (K=128 split 2) and gi (K=IN_K split 2), pk-fma ----
        v2f a0 = mkv2(bgh, 0.f), a1 = mkv2(0.f, 0.f);
        {
            const float4* h4 = (const float4*)&sm.hs[cur][kh * 64];
            #pragma unroll
            for (int k = 0; k < 16; k += 2) {
                float4 x0 = h4[k], x1 = h4[k + 1];
                a0 += whh[2 * k] * mkv2(x0.x, x0.y);
                a0 += whh[2 * k + 1] * mkv2(x0.z, x0.w);
                a1 += whh[2 * k + 2] * mkv2(x1.x, x1.y);
                a1 += whh[2 * k + 3] * mkv2(x1.z, x1.w);
            }
        }
        float sgh = a0.x + a0.y + a1.x + a1.y;
        v2f c0 = mkv2(bgi, 0.f), c1 = mkv2(0.f, 0.f);
        {
            const float4* x4 = (const float4*)&sm.xs[cur][kh * KI];
            #pragma unroll
            for (int k = 0; k < KI / 4; k += 2) {
                float4 x0 = x4[k], x1 = x4[k + 1];
                c0 += wih[2 * k] * mkv2(x0.x, x0.y);
                c0 += wih[2 * k + 1] * mkv2(x0.z, x0.w);
                c1 += wih[2 * k + 2] * mkv2(x1.x, x1.y);
                c1 += wih[2 * k + 3] * mkv2(x1.z, x1.w);
            }
        }
        float sgi = c0.x + c0.y + c1.x + c1.y;
        if (r < 2 * HH) {                 // r,z rows: only the sum is needed
            sm.pg[kh][r] = sgi + sgh;
        } else {                          // n rows: keep gi_n / gh_n separate
            sm.pg[kh][r] = sgi;
            sm.pghn[kh][r - 2 * HH] = sgh;
        }
        __syncthreads();

        const int nxt = cur ^ 1;
        // ---- gates (waves 0-1) / input stage (wave 2) / fc partials (waves 6-9) ----
        if (tid < HH) {
            const int j = tid;
            float g_r = sm.pg[0][j] + sm.pg[1][j];
            float g_z = sm.pg[0][j + HH] + sm.pg[1][j + HH];
            float gin = sm.pg[0][j + 2 * HH] + sm.pg[1][j + 2 * HH];
            float ghn = sm.pghn[0][j] + sm.pghn[1][j];
            float rg = fast_sigmoid(g_r);
            float zg = fast_sigmoid(g_z);
            float ng = fast_tanh(gin + rg * ghn);
            float hn = (1.f - zg) * ng + zg * sm.hs[cur][j];
            sm.hs[nxt][j] = hn;
            if (!L1) y0b[(size_t)t * HH + j] = f2bf(hn);
            if (t == TT - 1) hout[j] = hn;
        } else if (pidx >= 0 && pidx < NV) {
            if constexpr (L1) {
                float4 f; f.x = bf2f(pu.x); f.y = bf2f(pu.y); f.z = bf2f(pu.z); f.w = bf2f(pu.w);
                ((float4*)sm.xs[nxt])[pidx] = f;
            } else {
                ((float4*)sm.xs[nxt])[pidx] = pf;
            }
        }
        // fc partials for h_{t-1} = hs[cur]; mapping o=idx&31, ks=idx>>5:
        //   hs reads: 2 addresses/wave (broadcast) on 2 banks -> conflict-free
        //   fcw reads: bank (o + ks*16 + i) % 32 -> 32 lanes spread, <=2-way -> free
        if (L1 && tid >= 384 && tid < 640) {
            int idx = tid - 384, o = idx & 31, ks = idx >> 5;
            const float* hv = &sm.hs[cur][ks * 16];
            const float* wv = &sm.fcw[o * 129 + ks * 16];
            float s = 0.f;
            #pragma unroll
            for (int i = 0; i < 16; ++i) s = fmaf(hv[i], wv[i], s);
            sm.pfc[o * 9 + ks] = s;
        }
        __syncthreads();

        // ---- producer: publish progress every 8 steps (after barrier drains y0 stores) ----
        if (!L1 && (t & 7) == 7 && tid == 0) {
            __threadfence();
            __hip_atomic_store(flag, t + 1, __ATOMIC_RELAXED, __HIP_MEMORY_SCOPE_AGENT);
        }
        cur = nxt;
    }

    // ---- consumer epilogue: flush fc pipeline (steps TT-2, TT-1) ----
    if constexpr (L1) {
        if (tid >= 704 && tid < 736) {
            int o = tid - 704;
            float s = sm.fcb[o];
            #pragma unroll
            for (int j = 0; j < 8; ++j) s += sm.pfc[o * 9 + j];
            outb[(size_t)(TT - 2) * NOUT + o] = s;
        }
        __syncthreads();
        if (tid >= 384 && tid < 640) {   // partials for h_{TT-1} = hs[cur]
            int idx = tid - 384, o = idx & 31, ks = idx >> 5;
            const float* hv = &sm.hs[cur][ks * 16];
            const float* wv = &sm.fcw[o * 129 + ks * 16];
            float s = 0.f;
            #pragma unroll
            for (int i = 0; i < 16; ++i) s = fmaf(hv[i], wv[i], s);
            sm.pfc[o * 9 + ks] = s;
        }
        __syncthreads();
        if (tid >= 704 && tid < 736) {
            int o = tid - 704;
            float s = sm.fcb[o];
            #pragma unroll
            for (int j = 0; j < 8; ++j) s += sm.pfc[o * 9 + j];
            outb[(size_t)(TT - 1) * NOUT + o] = s;
        }
    }
}

// 768 threads = 12 waves = 3 waves/SIMD minimum. Second launch_bounds arg = min
// waves per EU (HIP semantics) = 3 -> VGPR cap 512/3 ~= 168, enough to keep the
// 128 weight floats/thread resident (round-2's 84-VGPR alloc spilled them).
extern "C" __global__ void __launch_bounds__(768, 3)
gru_fused_kernel(
    const float* x,
    const float* W_ih0, const float* W_hh0, const float* b_ih0, const float* b_hh0,
    const float* W_ih1, const float* W_hh1, const float* b_ih1, const float* b_hh1,
    const float* fc_w, const float* fc_b,
    float* out, float* hstack, ushort_t* y0, int* flags)
{
    __shared__ SM sm;
    const int wg = blockIdx.x;
    if (wg < BB) {
        gru_role<IN0, false>(sm, x, W_ih0, W_hh0, b_ih0, b_hh0,
                             y0, hstack + wg * HH, nullptr, nullptr, nullptr,
                             flags + wg, wg);
    } else {
        const int b = wg - BB;
        gru_role<HH, true>(sm, y0, W_ih1, W_hh1, b_ih1, b_hh1,
                           nullptr, hstack + BB * HH + b * HH,
                           out + (size_t)b * TT * NOUT, fc_w, fc_b,
                           flags + b, b);
    }
}

extern "C" void kernel_launch(void* const* d_in, const int* in_sizes, int n_in,
                              void* d_out, int out_size, void* d_ws, size_t ws_size,
                              hipStream_t stream) {
    const float* x     = (const float*)d_in[0];
    const float* W_ih0 = (const float*)d_in[1];
    const float* W_hh0 = (const float*)d_in[2];
    const float* b_ih0 = (const float*)d_in[3];
    const float* b_hh0 = (const float*)d_in[4];
    const float* W_ih1 = (const float*)d_in[5];
    const float* W_hh1 = (const float*)d_in[6];
    const float* b_ih1 = (const float*)d_in[7];
    const float* b_hh1 = (const float*)d_in[8];
    const float* fc_w  = (const float*)d_in[9];
    const float* fc_b  = (const float*)d_in[10];

    float* out    = (float*)d_out;                       // [B,T,32]
    float* hstack = out + (size_t)BB * TT * NOUT;        // [2,B,128]
    ushort_t* y0  = (ushort_t*)d_ws;                     // [B,T,128] bf16 (67 MB)
    int* flags    = (int*)((char*)d_ws + (96u << 20));   // 96 MB offset; poison 0xAA.. is
                                                         // negative as int -> consumer blocks

    gru_fused_kernel<<<2 * BB, 768, 0, stream>>>(
        x, W_ih0, W_hh0, b_ih0, b_hh0,
        W_ih1, W_hh1, b_ih1, b_hh1,
        fc_w, fc_b, out, hstack, y0, flags);
}

// Round 5
// 4839.706 us; speedup vs baseline: 1.9758x; 1.1397x over previous
//
#include <hip/hip_runtime.h>

#define BB 64
#define TT 4096
#define IN0 32
#define HH 128
#define G3 384
#define NOUT 32
#define RING 64
#define CH 8

typedef _Float16 h2 __attribute__((ext_vector_type(2)));
typedef _Float16 h8 __attribute__((ext_vector_type(8)));
union H8 { h8 v; h2 p[4]; };

// Per-WG LDS. pg/pgi stride 5 (coprime 32): scalar reads at [r*5+k] spread all banks.
struct SM {
    float pg[G3 * 5];        // gh partials (4-way K-split)
    float pgi[G3 * 5];       // gi partials (role A only)
    float hs[2][HH];         // hidden state fp32 (state + fc stay fp32)
    _Float16 hf[2][HH];      // f16 copy of h for the dot2 matvec
    _Float16 xh[2][IN0];     // role A: staged x in f16
    _Float16 ys[CH][HH];     // role B: staged y0 chunk
    float bias1[G3];         // b_ih
    float bias2[G3];         // b_hh
    float fcw[NOUT * 129];   // stride 129: bank(o*129+k)=(o+k)%32 conflict-free
    float fcb[NOUT];
    float pfc[NOUT * 9];
};

__device__ __forceinline__ float fast_sigmoid(float x) {
    x = fminf(fmaxf(x, -30.f), 30.f);
    float e = __expf(-x);
    return __builtin_amdgcn_rcpf(1.f + e);
}
__device__ __forceinline__ float fast_tanh(float x) {
    x = fminf(fmaxf(x, -15.f), 15.f);
    float e = __expf(-2.f * x);
    return (1.f - e) * __builtin_amdgcn_rcpf(1.f + e);
}
__device__ __forceinline__ float fdot2(h2 a, h2 b, float c) {
#if __has_builtin(__builtin_amdgcn_fdot2)
    return __builtin_amdgcn_fdot2(a, b, c, false);   // v_dot2_f32_f16, fp32 accum
#else
    return fmaf((float)a.x, (float)b.x, fmaf((float)a.y, (float)b.y, c));
#endif
}
__device__ __forceinline__ int aload(const int* p) {
    return __hip_atomic_load(p, __ATOMIC_RELAXED, __HIP_MEMORY_SCOPE_AGENT);
}
__device__ __forceinline__ void astore(int* p, int v) {
    __hip_atomic_store(p, v, __ATOMIC_RELAXED, __HIP_MEMORY_SCOPE_AGENT);
}
__device__ __forceinline__ h2 cvt2(float a, float b) {
    h2 r; r.x = (_Float16)a; r.y = (_Float16)b; return r;
}

// ---------------- Role A: layer-0 recurrence -> y0 (f16) ----------------
__device__ void role_A(SM& sm, const float* __restrict__ xb,
                       const float* __restrict__ W_ih, const float* __restrict__ W_hh,
                       const float* __restrict__ b_ih, const float* __restrict__ b_hh,
                       _Float16* __restrict__ y0b, float* __restrict__ hout, int* flagA)
{
    const int tid = threadIdx.x;
    const int rp = tid % 192, kq = tid / 192;          // thread = 2 rows x 32-K slice
    const int r0 = 2 * rp, r1 = r0 + 1;
    const int pA0 = r0 * 5 + kq, pA1 = r1 * 5 + kq;

    h2 wh0[16], wh1[16], wi0[4], wi1[4];
    #pragma unroll
    for (int i = 0; i < 16; ++i) {
        float2 f0 = *(const float2*)&W_hh[r0 * HH + kq * 32 + 2 * i];
        float2 f1 = *(const float2*)&W_hh[r1 * HH + kq * 32 + 2 * i];
        wh0[i] = cvt2(f0.x, f0.y); wh1[i] = cvt2(f1.x, f1.y);
    }
    #pragma unroll
    for (int i = 0; i < 4; ++i) {
        float2 f0 = *(const float2*)&W_ih[r0 * IN0 + kq * 8 + 2 * i];
        float2 f1 = *(const float2*)&W_ih[r1 * IN0 + kq * 8 + 2 * i];
        wi0[i] = cvt2(f0.x, f0.y); wi1[i] = cvt2(f1.x, f1.y);
    }
    for (int i = tid; i < G3; i += 768) { sm.bias1[i] = b_ih[i]; sm.bias2[i] = b_hh[i]; }
    if (tid < HH) { sm.hs[0][tid] = 0.f; sm.hf[0][tid] = (_Float16)0.f; }
    if (tid < 8) {
        float4 f = ((const float4*)xb)[tid];
        ((h2*)&sm.xh[0][0])[2 * tid]     = cvt2(f.x, f.y);
        ((h2*)&sm.xh[0][0])[2 * tid + 1] = cvt2(f.z, f.w);
    }
    __syncthreads();

    int cur = 0;
    for (int t = 0; t < TT; ++t) {
        float4 pf;
        if (tid >= 128 && tid < 136) {                 // prefetch x[t+1]
            int tn = (t + 1 < TT) ? t + 1 : t;
            pf = ((const float4*)(xb + (size_t)tn * IN0))[tid - 128];
        }
        // gh partials: 2 rows x 32 K, h from LDS f16 broadcast
        const h8* hv = (const h8*)&sm.hf[cur][kq * 32];
        float a0 = 0.f, a1 = 0.f;
        #pragma unroll
        for (int i = 0; i < 4; ++i) {
            H8 hh; hh.v = hv[i];
            #pragma unroll
            for (int j = 0; j < 4; ++j) {
                a0 = fdot2(wh0[4 * i + j], hh.p[j], a0);
                a1 = fdot2(wh1[4 * i + j], hh.p[j], a1);
            }
        }
        sm.pg[pA0] = a0; sm.pg[pA1] = a1;
        // gi partials: 2 rows x 8 K
        H8 xx; xx.v = ((const h8*)&sm.xh[cur][0])[kq];
        float c0 = 0.f, c1 = 0.f;
        #pragma unroll
        for (int j = 0; j < 4; ++j) {
            c0 = fdot2(wi0[j], xx.p[j], c0);
            c1 = fdot2(wi1[j], xx.p[j], c1);
        }
        sm.pgi[pA0] = c0; sm.pgi[pA1] = c1;
        __syncthreads();

        const int nxt = cur ^ 1;
        if (tid < HH) {
            const int j = tid;
            float gir = sm.pgi[j*5+0]+sm.pgi[j*5+1]+sm.pgi[j*5+2]+sm.pgi[j*5+3] + sm.bias1[j];
            float giz = sm.pgi[(j+HH)*5+0]+sm.pgi[(j+HH)*5+1]+sm.pgi[(j+HH)*5+2]+sm.pgi[(j+HH)*5+3] + sm.bias1[j+HH];
            float gin = sm.pgi[(j+2*HH)*5+0]+sm.pgi[(j+2*HH)*5+1]+sm.pgi[(j+2*HH)*5+2]+sm.pgi[(j+2*HH)*5+3] + sm.bias1[j+2*HH];
            float ghr = sm.pg[j*5+0]+sm.pg[j*5+1]+sm.pg[j*5+2]+sm.pg[j*5+3] + sm.bias2[j];
            float ghz = sm.pg[(j+HH)*5+0]+sm.pg[(j+HH)*5+1]+sm.pg[(j+HH)*5+2]+sm.pg[(j+HH)*5+3] + sm.bias2[j+HH];
            float ghn = sm.pg[(j+2*HH)*5+0]+sm.pg[(j+2*HH)*5+1]+sm.pg[(j+2*HH)*5+2]+sm.pg[(j+2*HH)*5+3] + sm.bias2[j+2*HH];
            float rg = fast_sigmoid(gir + ghr);
            float zg = fast_sigmoid(giz + ghz);
            float ng = fast_tanh(gin + rg * ghn);
            float hn = (1.f - zg) * ng + zg * sm.hs[cur][j];
            sm.hs[nxt][j] = hn;
            sm.hf[nxt][j] = (_Float16)hn;
            y0b[(size_t)t * HH + j] = (_Float16)hn;
            if (t == TT - 1) hout[j] = hn;
        } else if (tid < 136) {
            int i = tid - 128;
            ((h2*)&sm.xh[nxt][0])[2 * i]     = cvt2(pf.x, pf.y);
            ((h2*)&sm.xh[nxt][0])[2 * i + 1] = cvt2(pf.z, pf.w);
        }
        __syncthreads();
        if ((t & 7) == 7 && tid == 0) { __threadfence(); astore(flagA, t + 1); }
        cur = nxt;
    }
}

// ---------------- Role B: gi1 = W_ih1 * y0 + b_ih1 -> ring ----------------
__device__ void role_B(SM& sm, const _Float16* __restrict__ y0b,
                       const float* __restrict__ W_ih, const float* __restrict__ b_ih,
                       float* __restrict__ ring, int* flagA, int* flagB, int* flagC)
{
    const int tid = threadIdx.x;
    const int rp = tid % 192, kq = tid / 192;
    const int r0 = 2 * rp, r1 = r0 + 1;
    const int pA0 = r0 * 5 + kq, pA1 = r1 * 5 + kq;

    h2 wi0[16], wi1[16];
    #pragma unroll
    for (int i = 0; i < 16; ++i) {
        float2 f0 = *(const float2*)&W_ih[r0 * HH + kq * 32 + 2 * i];
        float2 f1 = *(const float2*)&W_ih[r1 * HH + kq * 32 + 2 * i];
        wi0[i] = cvt2(f0.x, f0.y); wi1[i] = cvt2(f1.x, f1.y);
    }
    for (int i = tid; i < G3; i += 768) sm.bias1[i] = b_ih[i];

    for (int T0 = 0; T0 < TT; T0 += CH) {
        if (tid == 0) {
            while (aload(flagA) < T0 + CH) __builtin_amdgcn_s_sleep(2);
            int need = T0 + CH - RING;       // ring slot reuse safety
            while (aload(flagC) < need) __builtin_amdgcn_s_sleep(2);
            __threadfence();
        }
        __syncthreads();
        for (int i = tid; i < CH * HH / 2; i += 768)   // stage y0 chunk (f16)
            ((unsigned*)sm.ys)[i] = ((const unsigned*)(y0b + (size_t)T0 * HH))[i];
        __syncthreads();
        for (int s = 0; s < CH; ++s) {
            const h8* yv = (const h8*)&sm.ys[s][kq * 32];
            float a0 = 0.f, a1 = 0.f;
            #pragma unroll
            for (int i = 0; i < 4; ++i) {
                H8 yy; yy.v = yv[i];
                #pragma unroll
                for (int j = 0; j < 4; ++j) {
                    a0 = fdot2(wi0[4 * i + j], yy.p[j], a0);
                    a1 = fdot2(wi1[4 * i + j], yy.p[j], a1);
                }
            }
            sm.pg[pA0] = a0; sm.pg[pA1] = a1;
            __syncthreads();
            if (tid < G3) {
                float sum = sm.pg[tid*5+0]+sm.pg[tid*5+1]+sm.pg[tid*5+2]+sm.pg[tid*5+3] + sm.bias1[tid];
                ring[(size_t)((T0 + s) & (RING - 1)) * G3 + tid] = sum;
            }
            __syncthreads();
        }
        if (tid == 0) { __threadfence(); astore(flagB, T0 + CH); }
    }
}

// ---------------- Role C: layer-1 recurrence + fused fc -> out ----------------
__device__ void role_C(SM& sm, const float* __restrict__ ring,
                       const float* __restrict__ W_hh, const float* __restrict__ b_hh,
                       const float* __restrict__ fc_w, const float* __restrict__ fc_b,
                       float* __restrict__ outb, float* __restrict__ hout,
                       int* flagB, int* flagC)
{
    const int tid = threadIdx.x;
    const int rp = tid % 192, kq = tid / 192;
    const int r0 = 2 * rp, r1 = r0 + 1;
    const int pA0 = r0 * 5 + kq, pA1 = r1 * 5 + kq;

    h2 wh0[16], wh1[16];
    #pragma unroll
    for (int i = 0; i < 16; ++i) {
        float2 f0 = *(const float2*)&W_hh[r0 * HH + kq * 32 + 2 * i];
        float2 f1 = *(const float2*)&W_hh[r1 * HH + kq * 32 + 2 * i];
        wh0[i] = cvt2(f0.x, f0.y); wh1[i] = cvt2(f1.x, f1.y);
    }
    if (tid == 0) astore(flagC, 0);          // unblock B's ring-space check
    for (int i = tid; i < G3; i += 768) sm.bias2[i] = b_hh[i];
    for (int i = tid; i < NOUT * HH; i += 768)
        sm.fcw[(i >> 7) * 129 + (i & 127)] = fc_w[i];
    if (tid < NOUT) sm.fcb[tid] = fc_b[tid];
    if (tid < HH) { sm.hs[0][tid] = 0.f; sm.hf[0][tid] = (_Float16)0.f; }
    __syncthreads();

    int cur = 0;
    for (int t = 0; t < TT; ++t) {
        if ((t & 7) == 0) {
            if (tid == 0) {
                while (aload(flagB) < t + CH) __builtin_amdgcn_s_sleep(2);
                __threadfence();
            }
            __syncthreads();
        }
        // fc reduce for step t-2
        if (t >= 2 && tid >= 704 && tid < 736) {
            int o = tid - 704;
            float s = sm.fcb[o];
            #pragma unroll
            for (int j = 0; j < 8; ++j) s += sm.pfc[o * 9 + j];
            outb[(size_t)(t - 2) * NOUT + o] = s;
        }
        // prefetch gi1[t] from ring (used after the barrier)
        float gir = 0.f, giz = 0.f, gin = 0.f;
        if (tid < HH) {
            const float* rr = ring + (size_t)(t & (RING - 1)) * G3;
            gir = rr[tid]; giz = rr[tid + HH]; gin = rr[tid + 2 * HH];
        }
        // gh partials
        const h8* hv = (const h8*)&sm.hf[cur][kq * 32];
        float a0 = 0.f, a1 = 0.f;
        #pragma unroll
        for (int i = 0; i < 4; ++i) {
            H8 hh; hh.v = hv[i];
            #pragma unroll
            for (int j = 0; j < 4; ++j) {
                a0 = fdot2(wh0[4 * i + j], hh.p[j], a0);
                a1 = fdot2(wh1[4 * i + j], hh.p[j], a1);
            }
        }
        sm.pg[pA0] = a0; sm.pg[pA1] = a1;
        __syncthreads();

        const int nxt = cur ^ 1;
        if (tid < HH) {
            const int j = tid;
            float ghr = sm.pg[j*5+0]+sm.pg[j*5+1]+sm.pg[j*5+2]+sm.pg[j*5+3] + sm.bias2[j];
            float ghz = sm.pg[(j+HH)*5+0]+sm.pg[(j+HH)*5+1]+sm.pg[(j+HH)*5+2]+sm.pg[(j+HH)*5+3] + sm.bias2[j+HH];
            float ghn = sm.pg[(j+2*HH)*5+0]+sm.pg[(j+2*HH)*5+1]+sm.pg[(j+2*HH)*5+2]+sm.pg[(j+2*HH)*5+3] + sm.bias2[j+2*HH];
            float rg = fast_sigmoid(gir + ghr);
            float zg = fast_sigmoid(giz + ghz);
            float ng = fast_tanh(gin + rg * ghn);
            float hn = (1.f - zg) * ng + zg * sm.hs[cur][j];
            sm.hs[nxt][j] = hn;
            sm.hf[nxt][j] = (_Float16)hn;
            if (t == TT - 1) hout[j] = hn;
        }
        if (tid >= 384 && tid < 640) {   // fc partials for h_{t-1} = hs[cur]
            int idx = tid - 384, o = idx & 31, ks = idx >> 5;
            const float* hv2 = &sm.hs[cur][ks * 16];
            const float* wv = &sm.fcw[o * 129 + ks * 16];
            float s = 0.f;
            #pragma unroll
            for (int i = 0; i < 16; ++i) s = fmaf(hv2[i], wv[i], s);
            sm.pfc[o * 9 + ks] = s;
        }
        __syncthreads();
        if ((t & 7) == 7 && tid == 0) { __threadfence(); astore(flagC, t + 1); }
        cur = nxt;
    }
    // fc pipeline flush
    if (tid >= 704 && tid < 736) {
        int o = tid - 704;
        float s = sm.fcb[o];
        #pragma unroll
        for (int j = 0; j < 8; ++j) s += sm.pfc[o * 9 + j];
        outb[(size_t)(TT - 2) * NOUT + o] = s;
    }
    __syncthreads();
    if (tid >= 384 && tid < 640) {
        int idx = tid - 384, o = idx & 31, ks = idx >> 5;
        const float* hv2 = &sm.hs[cur][ks * 16];
        const float* wv = &sm.fcw[o * 129 + ks * 16];
        float s = 0.f;
        #pragma unroll
        for (int i = 0; i < 16; ++i) s = fmaf(hv2[i], wv[i], s);
        sm.pfc[o * 9 + ks] = s;
    }
    __syncthreads();
    if (tid >= 704 && tid < 736) {
        int o = tid - 704;
        float s = sm.fcb[o];
        #pragma unroll
        for (int j = 0; j < 8; ++j) s += sm.pfc[o * 9 + j];
        outb[(size_t)(TT - 1) * NOUT + o] = s;
    }
}

extern "C" __global__ void __launch_bounds__(768, 3)
gru_pipe_kernel(
    const float* x,
    const float* W_ih0, const float* W_hh0, const float* b_ih0, const float* b_hh0,
    const float* W_ih1, const float* W_hh1, const float* b_ih1, const float* b_hh1,
    const float* fc_w, const float* fc_b,
    float* out, float* hstack, _Float16* y0, float* ring, int* flags)
{
    __shared__ SM sm;
    const int wg = blockIdx.x;
    if (wg < BB) {
        const int b = wg;
        role_A(sm, x + (size_t)b * TT * IN0, W_ih0, W_hh0, b_ih0, b_hh0,
               y0 + (size_t)b * TT * HH, hstack + b * HH,
               &flags[(0 * 64 + b) * 16]);
    } else if (wg < 2 * BB) {
        const int b = wg - BB;
        role_B(sm, y0 + (size_t)b * TT * HH, W_ih1, b_ih1,
               ring + (size_t)b * RING * G3,
               &flags[(0 * 64 + b) * 16], &flags[(1 * 64 + b) * 16], &flags[(2 * 64 + b) * 16]);
    } else {
        const int b = wg - 2 * BB;
        role_C(sm, ring + (size_t)b * RING * G3, W_hh1, b_hh1, fc_w, fc_b,
               out + (size_t)b * TT * NOUT, hstack + BB * HH + b * HH,
               &flags[(1 * 64 + b) * 16], &flags[(2 * 64 + b) * 16]);
    }
}

extern "C" void kernel_launch(void* const* d_in, const int* in_sizes, int n_in,
                              void* d_out, int out_size, void* d_ws, size_t ws_size,
                              hipStream_t stream) {
    const float* x     = (const float*)d_in[0];
    const float* W_ih0 = (const float*)d_in[1];
    const float* W_hh0 = (const float*)d_in[2];
    const float* b_ih0 = (const float*)d_in[3];
    const float* b_hh0 = (const float*)d_in[4];
    const float* W_ih1 = (const float*)d_in[5];
    const float* W_hh1 = (const float*)d_in[6];
    const float* b_ih1 = (const float*)d_in[7];
    const float* b_hh1 = (const float*)d_in[8];
    const float* fc_w  = (const float*)d_in[9];
    const float* fc_b  = (const float*)d_in[10];

    float* out    = (float*)d_out;                        // [B,T,32]
    float* hstack = out + (size_t)BB * TT * NOUT;         // [2,B,128]
    _Float16* y0  = (_Float16*)d_ws;                      // [B,T,128] f16 (67.1 MB)
    float* ring   = (float*)((char*)d_ws + (68ull << 20)); // [B,RING,384] fp32 (6.3 MB)
    int* flags    = (int*)((char*)d_ws + (80ull << 20));   // 3*64 flags, 64-B stride;
                                                           // poison 0xAA.. = negative -> waiters block

    gru_pipe_kernel<<<3 * BB, 768, 0, stream>>>(
        x, W_ih0, W_hh0, b_ih0, b_hh0,
        W_ih1, W_hh1, b_ih1, b_hh1,
        fc_w, fc_b, out, hstack, y0, ring, flags);
}